// Round 1
// baseline (209.443 us; speedup 1.0000x reference)
//
#include <hip/hip_runtime.h>
#include <math.h>

// FD step, matching float32(1e-4)
#define HF 1e-4f

// smooth_step constants: LOW = pi/2 - pi/8, width = pi/4 (computed in f32 like jnp weak-typed scalars)
#define LOW_F  1.1780972450961724f
#define INV_TW 1.2732395447351628f   // 1/(pi/4) = 4/pi

__device__ __forceinline__ float pot_eval(float x, float y, float z,
                                          float a, float b,
                                          float dx, float dy, float dz) {
    float r2 = x * x + y * y + z * z;
    float r = sqrtf(r2);
    if (r == 0.0f) return 0.0f;              // origin -> 0 (matches jnp.where)
    float invr = 1.0f / r;
    float dot = (x * dx + y * dy + z * dz) * invr;
    dot = fminf(fmaxf(dot, -1.0f), 1.0f);
    float theta = acosf(dot);
    float t = (theta - LOW_F) * INV_TW;
    t = fminf(fmaxf(t, 0.0f), 1.0f);
    float w = t * t * (3.0f - 2.0f * t);
    // 0.5*a*r2 + (1-w)*0.5*b*r2*theta^2
    return 0.5f * a * r2 + (1.0f - w) * (0.5f * b) * r2 * theta * theta;
}

__device__ __forceinline__ void point_velocity(float x, float y, float z,
                                               float a, float b,
                                               float dx, float dy, float dz,
                                               float& vx, float& vy, float& vz) {
    const float inv2H = 1.0f / 2e-4f;   // matches (u+ - u-)/(2H) to <=1 ulp
    float upx = pot_eval(x + HF, y, z, a, b, dx, dy, dz);
    float umx = pot_eval(x - HF, y, z, a, b, dx, dy, dz);
    float upy = pot_eval(x, y + HF, z, a, b, dx, dy, dz);
    float umy = pot_eval(x, y - HF, z, a, b, dx, dy, dz);
    float upz = pot_eval(x, y, z + HF, a, b, dx, dy, dz);
    float umz = pot_eval(x, y, z - HF, a, b, dx, dy, dz);
    vx = -(upx - umx) * inv2H;
    vy = -(upy - umy) * inv2H;
    vz = -(upz - umz) * inv2H;
}

extern "C" __global__ void __launch_bounds__(256)
canyon3d_fd_kernel(const float* __restrict__ xyz,
                   const float* __restrict__ a_param,
                   const float* __restrict__ b_param,
                   const float* __restrict__ dir,
                   float* __restrict__ out,
                   int B) {
    int t = blockIdx.x * blockDim.x + threadIdx.x;
    int base = t * 4;                        // first point handled by this thread
    if (base >= B) return;

    float a = fminf(fmaxf(a_param[0], 0.0f), 20.0f);
    float b = fminf(fmaxf(b_param[0], 0.0f), 20.0f);
    float dx = dir[0], dy = dir[1], dz = dir[2];

    if (base + 4 <= B) {
        // fast path: 4 points = 12 floats = 3 aligned float4 loads/stores
        const float4* in4 = (const float4*)xyz;
        float4 A = in4[3 * t + 0];
        float4 Bv = in4[3 * t + 1];
        float4 C = in4[3 * t + 2];
        float p[12] = {A.x, A.y, A.z, A.w, Bv.x, Bv.y, Bv.z, Bv.w, C.x, C.y, C.z, C.w};
        float o[12];
#pragma unroll
        for (int i = 0; i < 4; ++i) {
            float vx, vy, vz;
            point_velocity(p[3 * i], p[3 * i + 1], p[3 * i + 2], a, b, dx, dy, dz, vx, vy, vz);
            o[3 * i] = vx; o[3 * i + 1] = vy; o[3 * i + 2] = vz;
        }
        float4* out4 = (float4*)out;
        out4[3 * t + 0] = make_float4(o[0], o[1], o[2], o[3]);
        out4[3 * t + 1] = make_float4(o[4], o[5], o[6], o[7]);
        out4[3 * t + 2] = make_float4(o[8], o[9], o[10], o[11]);
    } else {
        // tail: scalar per-point
        for (int i = base; i < B; ++i) {
            float x = xyz[3 * i], y = xyz[3 * i + 1], z = xyz[3 * i + 2];
            float vx, vy, vz;
            point_velocity(x, y, z, a, b, dx, dy, dz, vx, vy, vz);
            out[3 * i] = vx; out[3 * i + 1] = vy; out[3 * i + 2] = vz;
        }
    }
}

extern "C" void kernel_launch(void* const* d_in, const int* in_sizes, int n_in,
                              void* d_out, int out_size, void* d_ws, size_t ws_size,
                              hipStream_t stream) {
    const float* xyz = (const float*)d_in[0];
    const float* a_param = (const float*)d_in[1];
    const float* b_param = (const float*)d_in[2];
    const float* dir = (const float*)d_in[3];
    float* out = (float*)d_out;

    int B = in_sizes[0] / 3;
    int nthreads = (B + 3) / 4;
    dim3 block(256);
    dim3 grid((nthreads + 255) / 256);
    canyon3d_fd_kernel<<<grid, block, 0, stream>>>(xyz, a_param, b_param, dir, out, B);
}

// Round 2
// 185.117 us; speedup vs baseline: 1.1314x; 1.1314x over previous
//
#include <hip/hip_runtime.h>
#include <math.h>

// FD step, matching float32(1e-4)
#define HF 1e-4f

// smooth_step constants: LOW = pi/2 - pi/8, width = pi/4
#define LOW_F  1.1780972450961724f
#define INV_TW 1.2732395447351628f   // 4/pi (mul-by-reciprocal calibrated in R1: passed 0.53)

// Branchless acos, Cephes single-precision asin core (~1-2 ulp).
// small |x|<=0.5: acos(x) = pi/2 - asin(x)
// big   |x|> 0.5: z=(1-|x|)/2, acos(|x|)=2*asin(sqrt(z)); negative: pi - that
__device__ __forceinline__ float fast_acos(float x) {
    float s = __builtin_fabsf(x);
    bool big = s > 0.5f;
    float z = big ? fmaf(-0.5f, s, 0.5f) : x * x;
    float r = big ? __builtin_amdgcn_sqrtf(z) : s;
    float p = fmaf(z, 4.2163199048e-2f, 2.4181311049e-2f);
    p = fmaf(z, p, 4.5470025998e-2f);
    p = fmaf(z, p, 7.4953002686e-2f);
    p = fmaf(z, p, 1.6666752422e-1f);
    float asn = fmaf(r * z, p, r);                 // asin(r), r >= 0
    float t2 = 2.0f * asn;
    float rb = (x >= 0.0f) ? t2 : (3.14159274f - t2);        // big branch
    float rs = (x >= 0.0f) ? (1.57079637f - asn) : (1.57079637f + asn); // small branch
    return big ? rb : rs;
}

__device__ __forceinline__ float pot_eval(float x, float y, float z,
                                          float halfa, float halfb,
                                          float dx, float dy, float dz) {
    float r2 = x * x + y * y + z * z;
    float r = __builtin_amdgcn_sqrtf(r2);
    float invr = __builtin_amdgcn_rcpf(r);
    float dot = (x * dx + y * dy + z * dz) * invr;
    dot = fminf(fmaxf(dot, -1.0f), 1.0f);
    float theta = fast_acos(dot);
    float t = (theta - LOW_F) * INV_TW;
    t = fminf(fmaxf(t, 0.0f), 1.0f);
    float w = t * t * (3.0f - 2.0f * t);
    // 0.5*a*r2 + (1-w)*0.5*b*r2*theta^2  (halfa=0.5a, halfb=0.5b exact for a=1,b=10)
    float pot = halfa * r2 + (1.0f - w) * halfb * r2 * theta * theta;
    return (r2 == 0.0f) ? 0.0f : pot;
}

__device__ __forceinline__ void point_velocity(float x, float y, float z,
                                               float halfa, float halfb,
                                               float dx, float dy, float dz,
                                               float& vx, float& vy, float& vz) {
    const float inv2H = 1.0f / 2e-4f;
    float upx = pot_eval(x + HF, y, z, halfa, halfb, dx, dy, dz);
    float umx = pot_eval(x - HF, y, z, halfa, halfb, dx, dy, dz);
    float upy = pot_eval(x, y + HF, z, halfa, halfb, dx, dy, dz);
    float umy = pot_eval(x, y - HF, z, halfa, halfb, dx, dy, dz);
    float upz = pot_eval(x, y, z + HF, halfa, halfb, dx, dy, dz);
    float umz = pot_eval(x, y, z - HF, halfa, halfb, dx, dy, dz);
    vx = -(upx - umx) * inv2H;
    vy = -(upy - umy) * inv2H;
    vz = -(upz - umz) * inv2H;
}

extern "C" __global__ void __launch_bounds__(256)
canyon3d_fd_kernel(const float* __restrict__ xyz,
                   const float* __restrict__ a_param,
                   const float* __restrict__ b_param,
                   const float* __restrict__ dir,
                   float* __restrict__ out,
                   int B) {
    int t = blockIdx.x * blockDim.x + threadIdx.x;
    int base = t * 4;
    if (base >= B) return;

    float a = fminf(fmaxf(a_param[0], 0.0f), 20.0f);
    float b = fminf(fmaxf(b_param[0], 0.0f), 20.0f);
    float halfa = 0.5f * a;
    float halfb = 0.5f * b;
    float dx = dir[0], dy = dir[1], dz = dir[2];

    if (base + 4 <= B) {
        const float4* in4 = (const float4*)xyz;
        float4 A  = in4[3 * t + 0];
        float4 Bv = in4[3 * t + 1];
        float4 C  = in4[3 * t + 2];

        float o0, o1, o2, o3, o4, o5, o6, o7, o8, o9, o10, o11;
        point_velocity(A.x, A.y, A.z,  halfa, halfb, dx, dy, dz, o0, o1, o2);
        point_velocity(A.w, Bv.x, Bv.y, halfa, halfb, dx, dy, dz, o3, o4, o5);
        point_velocity(Bv.z, Bv.w, C.x, halfa, halfb, dx, dy, dz, o6, o7, o8);
        point_velocity(C.y, C.z, C.w,  halfa, halfb, dx, dy, dz, o9, o10, o11);

        float4* out4 = (float4*)out;
        out4[3 * t + 0] = make_float4(o0, o1, o2, o3);
        out4[3 * t + 1] = make_float4(o4, o5, o6, o7);
        out4[3 * t + 2] = make_float4(o8, o9, o10, o11);
    } else {
        for (int i = base; i < B; ++i) {
            float x = xyz[3 * i], y = xyz[3 * i + 1], z = xyz[3 * i + 2];
            float vx, vy, vz;
            point_velocity(x, y, z, halfa, halfb, dx, dy, dz, vx, vy, vz);
            out[3 * i] = vx; out[3 * i + 1] = vy; out[3 * i + 2] = vz;
        }
    }
}

extern "C" void kernel_launch(void* const* d_in, const int* in_sizes, int n_in,
                              void* d_out, int out_size, void* d_ws, size_t ws_size,
                              hipStream_t stream) {
    const float* xyz = (const float*)d_in[0];
    const float* a_param = (const float*)d_in[1];
    const float* b_param = (const float*)d_in[2];
    const float* dir = (const float*)d_in[3];
    float* out = (float*)d_out;

    int B = in_sizes[0] / 3;
    int nthreads = (B + 3) / 4;
    dim3 block(256);
    dim3 grid((nthreads + 255) / 256);
    canyon3d_fd_kernel<<<grid, block, 0, stream>>>(xyz, a_param, b_param, dir, out, B);
}

// Round 3
// 184.784 us; speedup vs baseline: 1.1335x; 1.0018x over previous
//
#include <hip/hip_runtime.h>
#include <math.h>

// smooth_step constants: LOW = pi/2 - pi/8, ramp width TW = pi/4
#define LOW_F   1.1780972450961724f
#define INV_TW  1.2732395447351628f   // 4/pi
#define WP_K    7.639437268410977f    // 6 * INV_TW  (dw/dtheta = 6 t (1-t) / TW)

// Branchless acos, Cephes single-precision asin core (~1-2 ulp).
__device__ __forceinline__ float fast_acos(float x) {
    float s = __builtin_fabsf(x);
    bool big = s > 0.5f;
    float z = big ? fmaf(-0.5f, s, 0.5f) : x * x;
    float r = big ? __builtin_amdgcn_sqrtf(z) : s;
    float p = fmaf(z, 4.2163199048e-2f, 2.4181311049e-2f);
    p = fmaf(z, p, 4.5470025998e-2f);
    p = fmaf(z, p, 7.4953002686e-2f);
    p = fmaf(z, p, 1.6666752422e-1f);
    float asn = fmaf(r * z, p, r);
    float t2 = 2.0f * asn;
    float rb = (x >= 0.0f) ? t2 : (3.14159274f - t2);
    float rs = (x >= 0.0f) ? (1.57079637f - asn) : (1.57079637f + asn);
    return big ? rb : rs;
}

// Analytic velocity = -grad U,
// U = 0.5 a r^2 + 0.5 b r^2 theta^2 (1 - w(theta))
// v = -(a + b th^2 (1-w)) * xyz + k2 * (d - dot * p_hat)
// k2 = r * 0.5 b * (2 th (1-w) - th^2 w') / sin(th)
__device__ __forceinline__ void point_velocity(float x, float y, float z,
                                               float a, float b,
                                               float dx, float dy, float dz,
                                               float& vx, float& vy, float& vz) {
    float r2 = x * x + y * y + z * z;
    float r = __builtin_amdgcn_sqrtf(r2);
    float invr = __builtin_amdgcn_rcpf(r);
    float dot = (x * dx + y * dy + z * dz) * invr;
    dot = fminf(fmaxf(dot, -1.0f), 1.0f);
    float theta = fast_acos(dot);

    float t = (theta - LOW_F) * INV_TW;
    t = fminf(fmaxf(t, 0.0f), 1.0f);
    float w = t * t * (3.0f - 2.0f * t);
    float one_m_w = 1.0f - w;
    float wp = WP_K * t * (1.0f - t);              // dw/dtheta (0 outside ramp)

    float th2 = theta * theta;
    float k1 = fmaf(b * th2, one_m_w, a);          // a + b th^2 (1-w)

    float sin2 = fmaf(-dot, dot, 1.0f);            // 1 - dot^2
    float sinth = __builtin_amdgcn_sqrtf(fmaxf(sin2, 0.0f));
    float rcpsin = __builtin_amdgcn_rcpf(fmaxf(sinth, 1e-30f));
    float num = fmaf(2.0f * theta, one_m_w, -th2 * wp);  // 2 th (1-w) - th^2 w'
    float k2 = (r * 0.5f * b) * num * rcpsin;      // num==0 exactly at dot=+-1

    float m = dot * invr;                          // dot / r
    float gx = fmaf(-m, x, dx);                    // d - dot * p_hat
    float gy = fmaf(-m, y, dy);
    float gz = fmaf(-m, z, dz);

    float ovx = fmaf(-k1, x, k2 * gx);
    float ovy = fmaf(-k1, y, k2 * gy);
    float ovz = fmaf(-k1, z, k2 * gz);

    bool origin = (r2 == 0.0f);
    vx = origin ? 0.0f : ovx;
    vy = origin ? 0.0f : ovy;
    vz = origin ? 0.0f : ovz;
}

extern "C" __global__ void __launch_bounds__(256)
canyon3d_grad_kernel(const float* __restrict__ xyz,
                     const float* __restrict__ a_param,
                     const float* __restrict__ b_param,
                     const float* __restrict__ dir,
                     float* __restrict__ out,
                     int B) {
    int t = blockIdx.x * blockDim.x + threadIdx.x;
    int base = t * 4;
    if (base >= B) return;

    float a = fminf(fmaxf(a_param[0], 0.0f), 20.0f);
    float b = fminf(fmaxf(b_param[0], 0.0f), 20.0f);
    float dx = dir[0], dy = dir[1], dz = dir[2];

    if (base + 4 <= B) {
        const float4* in4 = (const float4*)xyz;
        float4 A  = in4[3 * t + 0];
        float4 Bv = in4[3 * t + 1];
        float4 C  = in4[3 * t + 2];

        float o0, o1, o2, o3, o4, o5, o6, o7, o8, o9, o10, o11;
        point_velocity(A.x, A.y, A.z,   a, b, dx, dy, dz, o0, o1, o2);
        point_velocity(A.w, Bv.x, Bv.y, a, b, dx, dy, dz, o3, o4, o5);
        point_velocity(Bv.z, Bv.w, C.x, a, b, dx, dy, dz, o6, o7, o8);
        point_velocity(C.y, C.z, C.w,   a, b, dx, dy, dz, o9, o10, o11);

        float4* out4 = (float4*)out;
        out4[3 * t + 0] = make_float4(o0, o1, o2, o3);
        out4[3 * t + 1] = make_float4(o4, o5, o6, o7);
        out4[3 * t + 2] = make_float4(o8, o9, o10, o11);
    } else {
        for (int i = base; i < B; ++i) {
            float x = xyz[3 * i], y = xyz[3 * i + 1], z = xyz[3 * i + 2];
            float vx, vy, vz;
            point_velocity(x, y, z, a, b, dx, dy, dz, vx, vy, vz);
            out[3 * i] = vx; out[3 * i + 1] = vy; out[3 * i + 2] = vz;
        }
    }
}

extern "C" void kernel_launch(void* const* d_in, const int* in_sizes, int n_in,
                              void* d_out, int out_size, void* d_ws, size_t ws_size,
                              hipStream_t stream) {
    const float* xyz = (const float*)d_in[0];
    const float* a_param = (const float*)d_in[1];
    const float* b_param = (const float*)d_in[2];
    const float* dir = (const float*)d_in[3];
    float* out = (float*)d_out;

    int B = in_sizes[0] / 3;
    int nthreads = (B + 3) / 4;
    dim3 block(256);
    dim3 grid((nthreads + 255) / 256);
    canyon3d_grad_kernel<<<grid, block, 0, stream>>>(xyz, a_param, b_param, dir, out, B);
}